// Round 5
// baseline (31.141 us; speedup 1.0000x reference)
//
#include <hip/hip_runtime.h>

// FFT convolution via N = 2^18 = 64 x 4096 Cooley-Tukey, 4 dispatches.
//   n = 4096*n1 + n2, k = k1 + 64*k2.
// KA : per-lane in-register 64-pt FFT over n1 (+ W_N^{-n2 k1})  -> A1[seq][k1][n2]
// KBf: one forward 4096-pt FFT per block (seq,k1)               -> Spec[seq][k1][k2]
// KBi: pointwise * 1/N + one inverse 4096-pt FFT (+ W_N^{+n2 k1}) -> D[z][k1][n2]
// KC : per-lane in-register 64-pt inverse FFT over k1, unpack.  -> out
// All global accesses lane-consecutive. 4096-FFT: double-buffered LDS, 3 barriers.

#define NTOT 262144
#define TLEN 131072
#define PI2_N    2.3968449808418217e-5f   /* 2*pi / 262144 */
#define PI2_4096 1.5339807878856412e-3f   /* 2*pi / 4096   */
#define LB(i) ((i) + ((i) >> 3))          /* LDS pad */

// W64^k = (cos, sin)(2*pi*k/64) — compile-time folded twiddles for the register FFT
constexpr float C64[64] = {
     1.000000000f,  0.995184727f,  0.980785280f,  0.956940336f,  0.923879533f,  0.881921264f,  0.831469612f,  0.773010453f,
     0.707106781f,  0.634393284f,  0.555570233f,  0.471396737f,  0.382683432f,  0.290284677f,  0.195090322f,  0.098017140f,
     0.000000000f, -0.098017140f, -0.195090322f, -0.290284677f, -0.382683432f, -0.471396737f, -0.555570233f, -0.634393284f,
    -0.707106781f, -0.773010453f, -0.831469612f, -0.881921264f, -0.923879533f, -0.956940336f, -0.980785280f, -0.995184727f,
    -1.000000000f, -0.995184727f, -0.980785280f, -0.956940336f, -0.923879533f, -0.881921264f, -0.831469612f, -0.773010453f,
    -0.707106781f, -0.634393284f, -0.555570233f, -0.471396737f, -0.382683432f, -0.290284677f, -0.195090322f, -0.098017140f,
     0.000000000f,  0.098017140f,  0.195090322f,  0.290284677f,  0.382683432f,  0.471396737f,  0.555570233f,  0.634393284f,
     0.707106781f,  0.773010453f,  0.831469612f,  0.881921264f,  0.923879533f,  0.956940336f,  0.980785280f,  0.995184727f };
constexpr float S64[64] = {
     0.000000000f,  0.098017140f,  0.195090322f,  0.290284677f,  0.382683432f,  0.471396737f,  0.555570233f,  0.634393284f,
     0.707106781f,  0.773010453f,  0.831469612f,  0.881921264f,  0.923879533f,  0.956940336f,  0.980785280f,  0.995184727f,
     1.000000000f,  0.995184727f,  0.980785280f,  0.956940336f,  0.923879533f,  0.881921264f,  0.831469612f,  0.773010453f,
     0.707106781f,  0.634393284f,  0.555570233f,  0.471396737f,  0.382683432f,  0.290284677f,  0.195090322f,  0.098017140f,
     0.000000000f, -0.098017140f, -0.195090322f, -0.290284677f, -0.382683432f, -0.471396737f, -0.555570233f, -0.634393284f,
    -0.707106781f, -0.773010453f, -0.831469612f, -0.881921264f, -0.923879533f, -0.956940336f, -0.980785280f, -0.995184727f,
    -1.000000000f, -0.995184727f, -0.980785280f, -0.956940336f, -0.923879533f, -0.881921264f, -0.831469612f, -0.773010453f,
    -0.707106781f, -0.634393284f, -0.555570233f, -0.471396737f, -0.382683432f, -0.290284677f, -0.195090322f, -0.098017140f };

__device__ __forceinline__ float2 cadd(float2 a, float2 b) { return make_float2(a.x + b.x, a.y + b.y); }
__device__ __forceinline__ float2 csub(float2 a, float2 b) { return make_float2(a.x - b.x, a.y - b.y); }
__device__ __forceinline__ float2 cmul(float2 a, float2 b) {
    return make_float2(a.x * b.x - a.y * b.y, a.x * b.y + a.y * b.x);
}
__device__ __forceinline__ float2 cexp_(float ang) {
    float s, c;
    __sincosf(ang, &s, &c);
    return make_float2(c, s);
}

template<int SIGN>
__device__ __forceinline__ void dft8(float2 x[8]) {
    const float R2 = 0.70710678118654752f;
    float2 t0 = cadd(x[0], x[4]), t1 = csub(x[0], x[4]);
    float2 t2 = cadd(x[2], x[6]), t3 = csub(x[2], x[6]);
    float2 u0 = cadd(x[1], x[5]), u1 = csub(x[1], x[5]);
    float2 u2 = cadd(x[3], x[7]), u3 = csub(x[3], x[7]);
    float2 it3 = (SIGN > 0) ? make_float2(-t3.y, t3.x) : make_float2(t3.y, -t3.x);
    float2 iu3 = (SIGN > 0) ? make_float2(-u3.y, u3.x) : make_float2(u3.y, -u3.x);
    float2 E0 = cadd(t0, t2), E2 = csub(t0, t2);
    float2 E1 = cadd(t1, it3), E3 = csub(t1, it3);
    float2 O0 = cadd(u0, u2), O2 = csub(u0, u2);
    float2 O1 = cadd(u1, iu3), O3 = csub(u1, iu3);
    float2 iO2 = (SIGN > 0) ? make_float2(-O2.y, O2.x) : make_float2(O2.y, -O2.x);
    float2 w1O1 = (SIGN > 0) ? make_float2(R2 * (O1.x - O1.y), R2 * (O1.y + O1.x))
                             : make_float2(R2 * (O1.x + O1.y), R2 * (O1.y - O1.x));
    float2 w3O3 = (SIGN > 0) ? make_float2(R2 * (-O3.x - O3.y), R2 * (O3.x - O3.y))
                             : make_float2(R2 * (O3.y - O3.x), R2 * (-O3.x - O3.y));
    x[0] = cadd(E0, O0);   x[4] = csub(E0, O0);
    x[1] = cadd(E1, w1O1); x[5] = csub(E1, w1O1);
    x[2] = cadd(E2, iO2);  x[6] = csub(E2, iO2);
    x[3] = cadd(E3, w3O3); x[7] = csub(E3, w3O3);
}

// dft8 with x[4..7] == 0 structurally
template<int SIGN>
__device__ __forceinline__ void dft8z(float2 x[8]) {
    const float R2 = 0.70710678118654752f;
    float2 x0 = x[0], x1 = x[1], x2 = x[2], x3 = x[3];
    float2 rx2 = (SIGN > 0) ? make_float2(-x2.y, x2.x) : make_float2(x2.y, -x2.x);
    float2 rx3 = (SIGN > 0) ? make_float2(-x3.y, x3.x) : make_float2(x3.y, -x3.x);
    float2 E0 = cadd(x0, x2), E2 = csub(x0, x2);
    float2 E1 = cadd(x0, rx2), E3 = csub(x0, rx2);
    float2 O0 = cadd(x1, x3), O2 = csub(x1, x3);
    float2 O1 = cadd(x1, rx3), O3 = csub(x1, rx3);
    float2 iO2 = (SIGN > 0) ? make_float2(-O2.y, O2.x) : make_float2(O2.y, -O2.x);
    float2 w1O1 = (SIGN > 0) ? make_float2(R2 * (O1.x - O1.y), R2 * (O1.y + O1.x))
                             : make_float2(R2 * (O1.x + O1.y), R2 * (O1.y - O1.x));
    float2 w3O3 = (SIGN > 0) ? make_float2(R2 * (-O3.x - O3.y), R2 * (O3.x - O3.y))
                             : make_float2(R2 * (O3.y - O3.x), R2 * (-O3.x - O3.y));
    x[0] = cadd(E0, O0);   x[4] = csub(E0, O0);
    x[1] = cadd(E1, w1O1); x[5] = csub(E1, w1O1);
    x[2] = cadd(E2, iO2);  x[6] = csub(E2, iO2);
    x[3] = cadd(E3, w3O3); x[7] = csub(E3, w3O3);
}

template<int SIGN>
__device__ __forceinline__ void twbase(float2 x[8], int base, float unit) {
#pragma unroll
    for (int i = 1; i < 8; ++i) {
        float ang = unit * (float)(base * i);
        x[i] = cmul(x[i], cexp_((SIGN < 0) ? -ang : ang));
    }
}

// In-register 64-pt FFT, radix-8 x radix-8, in-place, compile-time twiddles.
template<int SIGN, bool REVIN, bool HZ = false>
__device__ __forceinline__ void fft64_reg(float2 x[64]) {
#pragma unroll
    for (int t = 0; t < 8; ++t) {
        float2 g[8];
#pragma unroll
        for (int i = 0; i < 8; ++i) g[i] = REVIN ? x[8 * t + i] : x[t + 8 * i];
        if (HZ) dft8z<SIGN>(g); else dft8<SIGN>(g);
        if (t) {
#pragma unroll
            for (int i = 1; i < 8; ++i) {
                int j = (t * i) & 63;                       // compile-time
                float2 w = make_float2(C64[j], (SIGN < 0) ? -S64[j] : S64[j]);
                g[i] = cmul(g[i], w);
            }
        }
#pragma unroll
        for (int i = 0; i < 8; ++i) { if (REVIN) x[8 * t + i] = g[i]; else x[t + 8 * i] = g[i]; }
    }
#pragma unroll
    for (int t = 0; t < 8; ++t) {
        float2 g[8];
#pragma unroll
        for (int i = 0; i < 8; ++i) g[i] = REVIN ? x[t + 8 * i] : x[8 * t + i];
        dft8<SIGN>(g);
#pragma unroll
        for (int i = 0; i < 8; ++i) { if (REVIN) x[t + 8 * i] = g[i]; else x[8 * t + i] = g[i]; }
    }
}

// 4096-pt radix-8 Stockham FFT, 512 threads, double-buffered LDS, 3 barriers.
// x[i] = d[t + 512*i] natural order in and out.
template<int SIGN>
__device__ void fft4096_block(float2 x[8], int t, float2* L0, float2* L1) {
    dft8<SIGN>(x);
    twbase<SIGN>(x, t, PI2_4096);
#pragma unroll
    for (int i = 0; i < 8; ++i) L0[LB(8 * t + i)] = x[i];
    __syncthreads();
    {
        int q = t & 7, p = t >> 3;
#pragma unroll
        for (int i = 0; i < 8; ++i) x[i] = L0[LB(q + 8 * p + 512 * i)];
        dft8<SIGN>(x);
        twbase<SIGN>(x, 8 * p, PI2_4096);
#pragma unroll
        for (int i = 0; i < 8; ++i) L1[LB(q + 64 * p + 8 * i)] = x[i];
    }
    __syncthreads();
    {
        int q = t & 63, p = t >> 6;
#pragma unroll
        for (int i = 0; i < 8; ++i) x[i] = L1[LB(q + 64 * p + 512 * i)];
        dft8<SIGN>(x);
        twbase<SIGN>(x, 64 * p, PI2_4096);
#pragma unroll
        for (int i = 0; i < 8; ++i) L0[LB(q + 512 * p + 64 * i)] = x[i];
    }
    __syncthreads();
#pragma unroll
    for (int i = 0; i < 8; ++i) x[i] = L0[LB(t + 512 * i)];
    dft8<SIGN>(x);
}

// KA: 192 blocks x 64. seq = bid>>6 (0:c0+ic1, 1:c2+ic3, 2:flipped rir).
__global__ void __launch_bounds__(64, 1) ka(const float* __restrict__ audio,
                                            const float* __restrict__ rir,
                                            float2* __restrict__ A1) {
    int bid = blockIdx.x;
    int seq = bid >> 6;
    int n2 = ((bid & 63) << 6) + threadIdx.x;
    float2 x[64];
    if (seq < 2) {
        const float* c0 = audio + (size_t)(2 * seq) * TLEN;
        const float* c1 = c0 + TLEN;
#pragma unroll
        for (int n1 = 0; n1 < 32; ++n1) {
            int n = (n1 << 12) + n2;
            x[n1] = make_float2(c0[n], c1[n]);
        }
    } else {
#pragma unroll
        for (int n1 = 0; n1 < 32; ++n1) {
            int n = (n1 << 12) + n2;
            x[n1] = make_float2(rir[TLEN - 1 - n], 0.f);
        }
    }
#pragma unroll
    for (int n1 = 32; n1 < 64; ++n1) x[n1] = make_float2(0.f, 0.f);

    fft64_reg<-1, false, true>(x);

    float2* dst = A1 + ((size_t)seq << 18) + n2;
#pragma unroll
    for (int r = 0; r < 64; ++r) {
        int k1 = ((r & 7) << 3) | (r >> 3);   // rev8(r), compile-time
        float2 v = x[r];
        if (k1) v = cmul(v, cexp_(-PI2_N * (float)(n2 * k1)));
        dst[(size_t)k1 << 12] = v;
    }
}

// KBf: 192 blocks x 512. One forward 4096-FFT per (seq,k1) row.
__global__ void __launch_bounds__(512) kbf(const float2* __restrict__ A1,
                                           float2* __restrict__ Spec) {
    int t = threadIdx.x;
    __shared__ float2 L0[4608], L1[4608];
    const float2* src = A1 + ((size_t)blockIdx.x << 12);
    float2 x[8];
#pragma unroll
    for (int i = 0; i < 8; ++i) x[i] = src[t + 512 * i];
    fft4096_block<-1>(x, t, L0, L1);
    float2* dst = Spec + ((size_t)blockIdx.x << 12) + t;
#pragma unroll
    for (int i = 0; i < 8; ++i) dst[512 * i] = x[i];
}

// KBi: 128 blocks x 512. z = bid>>6, k1 = bid&63. Pointwise + inverse FFT + twiddle.
__global__ void __launch_bounds__(512) kbi(const float2* __restrict__ Spec,
                                           float2* __restrict__ D) {
    int z = blockIdx.x >> 6;
    int k1 = blockIdx.x & 63;
    int t = threadIdx.x;
    __shared__ float2 L0[4608], L1[4608];

    const float2* sz = Spec + (((size_t)z << 6) + k1 << 12);
    const float2* sr = Spec + (((size_t)128 + k1) << 12);
    float2 x[8], r8[8];
#pragma unroll
    for (int i = 0; i < 8; ++i) x[i] = sz[t + 512 * i];
#pragma unroll
    for (int i = 0; i < 8; ++i) r8[i] = sr[t + 512 * i];

    const float invN = 3.814697265625e-6f;  // 1/262144
#pragma unroll
    for (int i = 0; i < 8; ++i) {
        float2 y = cmul(x[i], r8[i]);
        x[i] = make_float2(y.x * invN, y.y * invN);
    }

    fft4096_block<1>(x, t, L0, L1);

    float2* d = D + ((size_t)blockIdx.x << 12) + t;
    if (k1) {
#pragma unroll
        for (int i = 0; i < 8; ++i) {
            int n2 = t + 512 * i;
            d[512 * i] = cmul(x[i], cexp_(PI2_N * (float)(n2 * k1)));
        }
    } else {
#pragma unroll
        for (int i = 0; i < 8; ++i) d[512 * i] = x[i];
    }
}

// KC: 128 blocks x 64. z = bid>>6. In-register 64-pt inverse FFT over k1, unpack.
__global__ void __launch_bounds__(64, 1) kc(const float2* __restrict__ D,
                                            float* __restrict__ out, int Lout) {
    int bid = blockIdx.x;
    int z = bid >> 6;
    int n2 = ((bid & 63) << 6) + threadIdx.x;

    float2 x[64];
    const float2* src = D + ((size_t)z << 18) + n2;
#pragma unroll
    for (int r = 0; r < 64; ++r) {
        int k1 = ((r & 7) << 3) | (r >> 3);   // load directly into rev layout
        x[r] = src[(size_t)k1 << 12];
    }

    fft64_reg<1, true>(x);                    // natural n1 out

    float* o0 = out + (size_t)(2 * z) * Lout;
    float* o1 = o0 + Lout;
#pragma unroll
    for (int n1 = 0; n1 < 64; ++n1) {
        int n = (n1 << 12) + n2;
        if (n < Lout) { o0[n] = x[n1].x; o1[n] = x[n1].y; }
    }
}

extern "C" void kernel_launch(void* const* d_in, const int* in_sizes, int n_in,
                              void* d_out, int out_size, void* d_ws, size_t ws_size,
                              hipStream_t stream) {
    const float* audio = (const float*)d_in[0];   // (1, 4, T) f32
    const float* rir   = (const float*)d_in[1];   // (T,) f32
    float* out = (float*)d_out;                   // (1, 4, 2T-1) f32
    int Lout = out_size / 4;                      // 262143

    float2* A1   = (float2*)d_ws;                 // 3 * 2^18 complex
    float2* Spec = A1 + 3 * NTOT;                 // 3 * 2^18 complex
    float2* D    = Spec + 3 * NTOT;               // 2 * 2^18 complex (16.8 MB total)

    ka <<<192, 64,  0, stream>>>(audio, rir, A1);
    kbf<<<192, 512, 0, stream>>>(A1, Spec);
    kbi<<<128, 512, 0, stream>>>(Spec, D);
    kc <<<128, 64,  0, stream>>>(D, out, Lout);
}